// Round 5
// baseline (91.413 us; speedup 1.0000x reference)
//
#include <hip/hip_runtime.h>

// ConvCapsuleLayer: B=2, 48x48, IN_CAPS=8, ATOMS=16, KER=3, OUT_CAPS=16, R=3.
// One 256-thread block per pixel (N=4232). Thread t=(o=t>>4, a=(t>>2)&3, c=t&3).
// Round-16: LDS-throughput attack. Per-block LDS-pipe arithmetic (b128~12cyc,
// shared pipe): phase B 36 b128/wave/round x 4 waves x 3 rounds + fused phase
// ~= 6.2K cyc/block x 16.5 blocks/CU ~= 101K cyc vs 103K wall -> LDS-bound.
//  - pose_t row register cache: pose_t[e][0..71] loaded ONCE into 18 v4f
//    (+72 VGPR), replacing 18 b128/thread/round with a single fill. ~28% of
//    per-block LDS traffic removed. __launch_bounds__(256,3) loosens the
//    VGPR budget to 170 (round-12 lesson: tight budget => spill catastrophe);
//    runtime occupancy follows actual usage (~127), not the bound.
//  - squash shortening: each lane's Z0..Z3 already hold s(a, c=0..3), so
//    sq = quad-local Z0^2+..+Z3^2 summed across 4 quads = 2 DPP hops (was 4),
//    and the c-select runs in parallel with the square-sum.
//  - keeps round-15's r=0 specialization + XCD swizzle (FETCH 8.3->1.5MB).

#define IN_CAPS 8
#define OUT_CAPS 16
#define KK 9
#define KKIN 72
#define BATCH 2
#define H_IN 48
#define W_IN 48
#define HO 46
#define WO 46
#define CIN 136
#define NPIX (BATCH*HO*WO)   // 4232 = 8*529

typedef float v2f __attribute__((ext_vector_type(2)));
typedef float v4f __attribute__((ext_vector_type(4)));

__device__ __forceinline__ v2f lo2(v4f v) { return __builtin_shufflevector(v, v, 0, 1); }
__device__ __forceinline__ v2f hi2(v4f v) { return __builtin_shufflevector(v, v, 2, 3); }
__device__ __forceinline__ v2f fma2(v2f a, v2f b, v2f c) {
    return __builtin_elementwise_fma(a, b, c);
}

template<int CTRL>
__device__ __forceinline__ float dpp_f(float x) {
    return __int_as_float(
        __builtin_amdgcn_update_dpp(0, __float_as_int(x), CTRL, 0xF, 0xF, true));
}

// pose_s row start: stride 20 + skew in {0,4} (round-11 verified layout)
__device__ __forceinline__ int pose_row(int k) {
    return k * 20 + ((k >> 3) & 1) * 4;
}
// G row start for (o, ic): stride 20 rows + 4*o skew (round-11 verified)
__device__ __forceinline__ int g_row(int o, int ic) {
    return (o * 8 + ic) * 20 + o * 4;
}

__global__ __launch_bounds__(256, 3)
void capsule_routing_kernel(const float* __restrict__ x,
                            const float* __restrict__ Wg,
                            float* __restrict__ out)
{
    __shared__ alignas(16) float pose_s[1440];             // skewed [k][atom] 5760 B
    __shared__ alignas(16) float pose_t[16 * 76];          // [a*4+b][k]      4864 B
    __shared__ alignas(16) float act_s[KKIN];              //                  288 B
    __shared__ alignas(16) float g_s[2620];                // G              10480 B
    __shared__ alignas(16) float coup_s[OUT_CAPS * 76];    // [o][k]          4864 B
    // total ~26.3 KB -> LDS cap 6 blocks/CU

    const int tid = threadIdx.x;
    const int o = tid >> 4;        // out capsule
    const int e = tid & 15;        // atom = a*4+c
    const int c = e & 3;

    // XCD-aware bijective swizzle: 4232 = 8*529; XCD (bx&7) gets a
    // contiguous 529-pixel slab (x slab ~350KB -> L2-resident).
    const int bx = blockIdx.x;
    const int n  = (bx & 7) * (NPIX / 8) + (bx >> 3);

    const int b   = n / (HO * WO);
    const int rem = n - b * (HO * WO);
    const int ho  = rem / WO;
    const int wo  = rem - ho * WO;

    // ---- W row fragment from global (L1-cached, identical for all blocks):
    //      w01[ic] = (W[ic][o][c][0], W[ic][o][c][1]), w23 = ([2],[3]) ----
    v2f w01[IN_CAPS], w23[IN_CAPS];
    #pragma unroll
    for (int i = 0; i < IN_CAPS; ++i) {
        const v4f wv = *reinterpret_cast<const v4f*>(
            &Wg[((i * OUT_CAPS + o) * 4 + c) * 4]);
        w01[i] = lo2(wv);
        w23[i] = hi2(wv);
    }

    // ---- 3x3 patch: 9 px x 136 ch; pose stored in BOTH layouts ----
    for (int idx = tid; idx < KK * CIN; idx += 256) {
        int p  = idx / CIN;
        int cc = idx - p * CIN;
        int py = p / 3, px = p - py * 3;
        float val = x[(((b * H_IN + ho + py) * W_IN) + (wo + px)) * CIN + cc];
        int ic = cc / 17;
        int aa = cc - ic * 17;
        int k  = p * IN_CAPS + ic;
        if (aa == 16) {
            act_s[k] = val;
        } else {
            pose_s[pose_row(k) + aa] = val;
            pose_t[aa * 76 + k] = val;
        }
    }
    __syncthreads();

    // fused-phase ownership: thread pair (k = tid>>1, hf = tid&1) owns
    // logits[k][hf*8+j], j=0..7, accumulated in lreg8 across rounds.
    const int kf  = tid >> 1;
    const int hf  = tid & 1;
    const int ick = kf & 7;
    float lreg8[8] = {0.f,0.f,0.f,0.f,0.f,0.f,0.f,0.f};

    const v4f* cp = reinterpret_cast<const v4f*>(&coup_s[o * 76]);
    const v4f* pp = reinterpret_cast<const v4f*>(&pose_t[e * 76]);
    const v4f* ap = reinterpret_cast<const v4f*>(act_s);

    // ---- pose_t row register cache: pose_t[e][0..71] read ONCE ----
    v4f pq[18];
    #pragma unroll
    for (int i = 0; i < 18; ++i) pq[i] = pp[i];

    float v = 0.f;

    // U[j] from M fragments + quad allreduce + squash -> this thread's v
    auto finishBU = [&](v2f M01, v2f M23, v2f M45, v2f M67, float mscale) {
        const float Mc[8] = {M01.x, M01.y, M23.x, M23.y,
                             M45.x, M45.y, M67.x, M67.y};
        v2f U01 = {0.f,0.f}, U23 = {0.f,0.f};
        #pragma unroll
        for (int ic = 0; ic < 8; ++ic) {
            const v2f mm = {Mc[ic], Mc[ic]};
            U01 = fma2(w01[ic], mm, U01);
            U23 = fma2(w23[ic], mm, U23);
        }
        const v2f sc = {mscale, mscale};
        U01 *= sc; U23 *= sc;
        // quad allreduce: Z[j] = s(a, c=j)
        float Z0 = U01.x, Z1 = U01.y, Z2 = U23.x, Z3 = U23.y;
        Z0 += dpp_f<0xB1>(Z0); Z1 += dpp_f<0xB1>(Z1);
        Z2 += dpp_f<0xB1>(Z2); Z3 += dpp_f<0xB1>(Z3);
        Z0 += dpp_f<0x4E>(Z0); Z1 += dpp_f<0x4E>(Z1);
        Z2 += dpp_f<0x4E>(Z2); Z3 += dpp_f<0x4E>(Z3);
        // sq directly from Z (quad-uniform), summed across the 4 quads of the
        // e-group: 2 DPP hops; runs in parallel with the c-select.
        float t = Z0*Z0 + Z1*Z1 + Z2*Z2 + Z3*Z3;
        t += dpp_f<0x124>(t);   // row_ror:4
        t += dpp_f<0x128>(t);   // row_ror:8
        const float s = (c == 0) ? Z0 : (c == 1) ? Z1 : (c == 2) ? Z2 : Z3;
        v = s * (t / ((1.f + t) * sqrtf(t + 1e-7f)));
    };

    // G build + fused logit-update/softmax -> writes coup_s for next round
    auto g_fused = [&]() {
        const float vq0 = dpp_f<0x00>(v);
        const float vq1 = dpp_f<0x55>(v);
        const float vq2 = dpp_f<0xAA>(v);
        const float vq3 = dpp_f<0xFF>(v);
        const v2f vq01 = {vq0, vq1};
        const v2f vq23 = {vq2, vq3};
        #pragma unroll
        for (int ic = 0; ic < 8; ++ic) {
            v2f h = fma2(w23[ic], vq23, w01[ic] * vq01);
            g_s[g_row(o, ic) + e] = h.x + h.y;
        }
        __syncthreads();
        if (tid < 2 * KKIN) {
            const v4f* pk = reinterpret_cast<const v4f*>(
                &pose_s[pose_row(kf)]);
            const v4f p0 = pk[0], p1 = pk[1], p2 = pk[2], p3 = pk[3];
            const v2f q0 = lo2(p0), q1 = hi2(p0), q2 = lo2(p1), q3 = hi2(p1);
            const v2f q4 = lo2(p2), q5 = hi2(p2), q6 = lo2(p3), q7 = hi2(p3);
            float lg[8];
            #pragma unroll
            for (int j = 0; j < 8; ++j) {
                const int oo = hf * 8 + j;
                const v4f* gp = reinterpret_cast<const v4f*>(
                    &g_s[g_row(oo, ick)]);
                const v4f g0 = gp[0], g1 = gp[1], g2 = gp[2], g3 = gp[3];
                v2f A = fma2(q2, lo2(g1), fma2(q4, lo2(g2),
                          fma2(q6, lo2(g3), q0 * lo2(g0))));
                v2f Bv = fma2(q3, hi2(g1), fma2(q5, hi2(g2),
                          fma2(q7, hi2(g3), q1 * hi2(g0))));
                lreg8[j] += (A.x + A.y) + (Bv.x + Bv.y);
                lg[j] = lreg8[j];
            }
            // softmax over 16 o: 8 local + pair combine via DPP xor1
            float mx = -1e30f;
            #pragma unroll
            for (int j = 0; j < 8; ++j) mx = fmaxf(mx, lg[j]);
            mx = fmaxf(mx, dpp_f<0xB1>(mx));
            float sum = 0.f;
            #pragma unroll
            for (int j = 0; j < 8; ++j) { lg[j] = __expf(lg[j] - mx); sum += lg[j]; }
            sum += dpp_f<0xB1>(sum);
            const float scale = act_s[kf] / sum;
            #pragma unroll
            for (int j = 0; j < 8; ++j)
                coup_s[(hf * 8 + j) * 76 + kf] = lg[j] * scale;
        }
        __syncthreads();
    };

    // ================= r = 0 (coup = act/16, o-independent) =================
    {
        v2f M01 = {0.f,0.f}, M23 = {0.f,0.f}, M45 = {0.f,0.f}, M67 = {0.f,0.f};
        #pragma unroll
        for (int p = 0; p < KK; ++p) {
            const v4f a0 = ap[2*p], a1 = ap[2*p+1];   // act[8p..8p+7], broadcast
            const v4f q0 = pq[2*p], q1 = pq[2*p+1];
            M01 = fma2(lo2(a0), lo2(q0), M01);
            M23 = fma2(hi2(a0), hi2(q0), M23);
            M45 = fma2(lo2(a1), lo2(q1), M45);
            M67 = fma2(hi2(a1), hi2(q1), M67);
        }
        finishBU(M01, M23, M45, M67, 0.0625f);   // fold 1/16 coupling here
        g_fused();
    }

    // ================= r = 1 =================
    {
        v2f M01 = {0.f,0.f}, M23 = {0.f,0.f}, M45 = {0.f,0.f}, M67 = {0.f,0.f};
        #pragma unroll
        for (int p = 0; p < KK; ++p) {
            const v4f c0 = cp[2*p], c1 = cp[2*p+1];
            const v4f q0 = pq[2*p], q1 = pq[2*p+1];
            M01 = fma2(lo2(c0), lo2(q0), M01);
            M23 = fma2(hi2(c0), hi2(q0), M23);
            M45 = fma2(lo2(c1), lo2(q1), M45);
            M67 = fma2(hi2(c1), hi2(q1), M67);
        }
        finishBU(M01, M23, M45, M67, 1.0f);
        g_fused();
    }

    // ================= r = 2 (no update afterwards) =================
    {
        v2f M01 = {0.f,0.f}, M23 = {0.f,0.f}, M45 = {0.f,0.f}, M67 = {0.f,0.f};
        #pragma unroll
        for (int p = 0; p < KK; ++p) {
            const v4f c0 = cp[2*p], c1 = cp[2*p+1];
            const v4f q0 = pq[2*p], q1 = pq[2*p+1];
            M01 = fma2(lo2(c0), lo2(q0), M01);
            M23 = fma2(hi2(c0), hi2(q0), M23);
            M45 = fma2(lo2(c1), lo2(q1), M45);
            M67 = fma2(hi2(c1), hi2(q1), M67);
        }
        finishBU(M01, M23, M45, M67, 1.0f);
    }

    // ---- out[n][o][e], coalesced (n = swizzled pixel id) ----
    out[n * 256 + tid] = v;
}

extern "C" void kernel_launch(void* const* d_in, const int* in_sizes, int n_in,
                              void* d_out, int out_size, void* d_ws, size_t ws_size,
                              hipStream_t stream) {
    const float* x  = (const float*)d_in[0];   // [2,48,48,136] fp32
    const float* Wt = (const float*)d_in[1];   // [8,16,4,4]    fp32
    float* outp = (float*)d_out;               // [2,46,46,16,16] fp32
    capsule_routing_kernel<<<dim3(NPIX), dim3(256), 0, stream>>>(x, Wt, outp);
}